// Round 10
// baseline (36.773 us; speedup 1.0000x reference)
//
#include <hip/hip_runtime.h>

#define SEQ 128
#define SD  15
#define REC 32    // floats per (b,s) record in dba_params
#define RPB 4     // rows per block
#define NT  (RPB * SEQ)   // 512 threads, 8 waves

// ---------------------------------------------------------------------------
// Single fused kernel (R5 structure, stores maximally front-loaded).
//  P0 : zero-column stores issued FIRST — no dependencies, so ~25 MB of the
//       write traffic drains underneath the load burst (R5 vs R6 showed
//       hidden-early stores beat minimal-late stores by ~6 us).
//  P1 : record-head loads (32 B of one 64 B line), dq -> LDS, pos shuffle-scan.
//  P2a: pos + t=0 quat stored immediately after the scan (pre-chain).
//  P2b: lanes 0..3 of wave 0 run the 127-step chains from LDS, quats -> LDS
//       (no global stores on the chain path — R7 showed those cost ~6 us).
//  P3 : post-barrier, only the s>=1 quat (4 floats, ~6 MB) is exposed.
// ---------------------------------------------------------------------------
__global__ __launch_bounds__(NT, 8) void fused_kernel(const float* __restrict__ dba,
                                                      const float* __restrict__ gt,
                                                      float* __restrict__ out,
                                                      int B) {
    const int tid  = threadIdx.x;
    const int row  = tid >> 7;          // 0..3
    const int s    = tid & (SEQ - 1);   // 0..127
    const int lane = tid & 63;
    const int half = s >> 6;            // which of the row's two waves
    const int r    = blockIdx.x * RPB + row;
    const bool valid = (r < B);

    __shared__ float4 sdq  [RPB][SEQ + 1];   // +1 pad: chain lanes on distinct banks
    __shared__ float4 squat[RPB][SEQ + 1];
    __shared__ float  ginit[RPB][8];
    __shared__ float  w0tot[RPB][3];

    float* o = out + ((size_t)r * SEQ + s) * SD;

    // ---- P0: dependency-free zero stores, issued before anything else ----
    if (valid) {
#pragma unroll
        for (int k = 7; k < SD; ++k) o[k] = 0.f;
    }

    // ---- P1: loads + pos scan ----
    float d0 = 0.f, d1 = 0.f, d2 = 0.f;
    if (valid) {
        const float* rec = dba + ((size_t)r * SEQ + s) * REC;
        const float4 h0 = *reinterpret_cast<const float4*>(rec);
        const float4 h1 = *reinterpret_cast<const float4*>(rec + 4);
        sdq[row][s] = make_float4(h0.w * 0.1f, h1.x * 0.1f, h1.y * 0.1f, h1.z * 0.1f);
        d0 = h0.x * 0.1f; d1 = h0.y * 0.1f; d2 = h0.z * 0.1f;
        if (s == 0) {
            const float* g = gt + (size_t)r * SEQ * SD;
            *reinterpret_cast<float4*>(&ginit[row][0]) = *reinterpret_cast<const float4*>(g);
            *reinterpret_cast<float4*>(&ginit[row][4]) = *reinterpret_cast<const float4*>(g + 4);
        }
    }

    float ix = d0, iy = d1, iz = d2;       // wave-local inclusive scan
#pragma unroll
    for (int off = 1; off < 64; off <<= 1) {
        const float tx = __shfl_up(ix, off, 64);
        const float ty = __shfl_up(iy, off, 64);
        const float tz = __shfl_up(iz, off, 64);
        if (lane >= off) { ix += tx; iy += ty; iz += tz; }
    }
    if (half == 0 && lane == 63) {
        w0tot[row][0] = ix; w0tot[row][1] = iy; w0tot[row][2] = iz;
    }
    __syncthreads();
    if (half == 1) { ix += w0tot[row][0]; iy += w0tot[row][1]; iz += w0tot[row][2]; }

    // ---- P2a: pos + t=0 quat stored pre-chain (hidden under chain) ----
    if (valid) {
        o[0] = ginit[row][0] + ix - d0;   // exclusive prefix = inclusive - own
        o[1] = ginit[row][1] + iy - d1;
        o[2] = ginit[row][2] + iz - d2;
        if (s == 0) {                     // t=0 quat: init_q, NOT normalized
            o[3] = ginit[row][3]; o[4] = ginit[row][4];
            o[5] = ginit[row][5]; o[6] = ginit[row][6];
        }
    }

    // ---- P2b: quaternion chains, lanes 0..3 of wave 0, quats -> LDS ----
    if (tid < RPB && blockIdx.x * RPB + tid < B) {
        const float4* srow = sdq[tid];
        float4*       qrow = squat[tid];
        float q0 = ginit[tid][3], q1 = ginit[tid][4],
              q2 = ginit[tid][5], q3 = ginit[tid][6];

#define QSTEP(C, T) do {                                                \
            q0 += (C).x; q1 += (C).y; q2 += (C).z; q3 += (C).w;         \
            const float a_ = q0 * q0 + q1 * q1;                         \
            const float b_ = q2 * q2 + q3 * q3;                         \
            const float i_ = __builtin_amdgcn_rsqf(a_ + b_);            \
            q0 *= i_; q1 *= i_; q2 *= i_; q3 *= i_;                     \
            qrow[T] = make_float4(q0, q1, q2, q3);                      \
        } while (0)

        float4 c0 = srow[0], c1 = srow[1], c2 = srow[2], c3 = srow[3],
               c4 = srow[4], c5 = srow[5], c6 = srow[6], c7 = srow[7];
        for (int w = 0; w < 15; ++w) {               // t = 1..120
            const float4* nx = srow + (w + 1) * 8;   // last window: srow[120..127]
            const float4 n0 = nx[0], n1 = nx[1], n2 = nx[2], n3 = nx[3],
                         n4 = nx[4], n5 = nx[5], n6 = nx[6], n7 = nx[7];
            const int t = w * 8 + 1;
            QSTEP(c0, t);     QSTEP(c1, t + 1); QSTEP(c2, t + 2); QSTEP(c3, t + 3);
            QSTEP(c4, t + 4); QSTEP(c5, t + 5); QSTEP(c6, t + 6); QSTEP(c7, t + 7);
            c0 = n0; c1 = n1; c2 = n2; c3 = n3;
            c4 = n4; c5 = n5; c6 = n6; c7 = n7;
        }
        QSTEP(c0, 121); QSTEP(c1, 122); QSTEP(c2, 123); QSTEP(c3, 124);
        QSTEP(c4, 125); QSTEP(c5, 126); QSTEP(c6, 127);
#undef QSTEP
    }
    __syncthreads();

    // ---- P3: only the s>=1 quat is exposed post-chain (~6 MB) ----
    if (valid && s > 0) {
        const float4 q = squat[row][s];
        o[3] = q.x; o[4] = q.y; o[5] = q.z; o[6] = q.w;
    }
}

extern "C" void kernel_launch(void* const* d_in, const int* in_sizes, int n_in,
                              void* d_out, int out_size, void* d_ws, size_t ws_size,
                              hipStream_t stream) {
    const float* dba = (const float*)d_in[0];   // (B, 128, 32)
    // d_in[1] = imu_measurements — unused by the reference
    const float* gt  = (const float*)d_in[2];   // (B, 128, 15)
    float* out = (float*)d_out;                 // (B, 128, 15)

    const int B = in_sizes[0] / (SEQ * REC);
    const int blocks = (B + RPB - 1) / RPB;
    fused_kernel<<<blocks, NT, 0, stream>>>(dba, gt, out, B);
}

// Round 11
// 30.571 us; speedup vs baseline: 1.2029x; 1.2029x over previous
//
#include <hip/hip_runtime.h>

#define SEQ 128
#define SD  15
#define REC 32    // floats per (b,s) record in dba_params
#define RPB 8     // rows per block (two groups of 4)
#define NT  512   // threads; each thread owns record s of rows (row) and (row+4)

// ---------------------------------------------------------------------------
// Single fused kernel, 8 rows/block, 512 blocks (2 blocks/CU resident).
// Store-placement rules distilled from R5..R9:
//   - loads issue FIRST (they feed the serial chains)         [R9 violated]
//   - non-quat stores (11/15 floats) issue pre-chain (hidden) [R5's win]
//   - only quat stores are post-chain
// New mechanism: at 2 blocks/CU the live output-line set is ~1.9 MB/XCD
// (< 4 MB L2), so post-chain quat stores merge into the still-dirty L2 lines
// from the pre-chain burst -> each line written to HBM once, and the exposed
// post-chain phase runs at L2 speed, not HBM speed.
// All 8 chains run in ONE window on lanes 0..7 of wave 0 (wave-lockstep:
// 8 chains cost the same ~1.7 us as 4).
// ---------------------------------------------------------------------------
__global__ __launch_bounds__(NT, 4) void fused_kernel(const float* __restrict__ dba,
                                                      const float* __restrict__ gt,
                                                      float* __restrict__ out,
                                                      int B) {
    const int tid  = threadIdx.x;
    const int row  = tid >> 7;          // 0..3 (group-A row)
    const int s    = tid & (SEQ - 1);   // 0..127
    const int lane = tid & 63;
    const int half = s >> 6;
    const int base = blockIdx.x * RPB;
    const int rA   = base + row;
    const int rB   = base + 4 + row;
    const bool vA = (rA < B), vB = (rB < B);

    __shared__ float4 sdq  [RPB][SEQ + 1];   // +1 pad: chain lanes on distinct banks
    __shared__ float4 squat[RPB][SEQ + 1];
    __shared__ float  ginit[RPB][8];
    __shared__ float  wtot [RPB][3];

    // ---- P1: ALL loads issue up front ----
    float4 a0 = make_float4(0,0,0,0), a1 = a0, b0 = a0, b1 = a0;
    if (vA) {
        const float* rec = dba + ((size_t)rA * SEQ + s) * REC;
        a0 = *reinterpret_cast<const float4*>(rec);
        a1 = *reinterpret_cast<const float4*>(rec + 4);
    }
    if (vB) {
        const float* rec = dba + ((size_t)rB * SEQ + s) * REC;
        b0 = *reinterpret_cast<const float4*>(rec);
        b1 = *reinterpret_cast<const float4*>(rec + 4);
    }
    if (s == 0) {
        if (vA) {
            const float* g = gt + (size_t)rA * SEQ * SD;
            *reinterpret_cast<float4*>(&ginit[row][0]) = *reinterpret_cast<const float4*>(g);
            *reinterpret_cast<float4*>(&ginit[row][4]) = *reinterpret_cast<const float4*>(g + 4);
        }
        if (vB) {
            const float* g = gt + (size_t)rB * SEQ * SD;
            *reinterpret_cast<float4*>(&ginit[row + 4][0]) = *reinterpret_cast<const float4*>(g);
            *reinterpret_cast<float4*>(&ginit[row + 4][4]) = *reinterpret_cast<const float4*>(g + 4);
        }
    }
    if (vA) sdq[row    ][s] = make_float4(a0.w * 0.1f, a1.x * 0.1f, a1.y * 0.1f, a1.z * 0.1f);
    if (vB) sdq[row + 4][s] = make_float4(b0.w * 0.1f, b1.x * 0.1f, b1.y * 0.1f, b1.z * 0.1f);

    // ---- dual shuffle scan (rows A and B interleaved for ILP) ----
    const float dA0 = a0.x * 0.1f, dA1 = a0.y * 0.1f, dA2 = a0.z * 0.1f;
    const float dB0 = b0.x * 0.1f, dB1 = b0.y * 0.1f, dB2 = b0.z * 0.1f;
    float xA = dA0, yA = dA1, zA = dA2, xB = dB0, yB = dB1, zB = dB2;
#pragma unroll
    for (int off = 1; off < 64; off <<= 1) {
        const float t0 = __shfl_up(xA, off, 64);
        const float t1 = __shfl_up(yA, off, 64);
        const float t2 = __shfl_up(zA, off, 64);
        const float t3 = __shfl_up(xB, off, 64);
        const float t4 = __shfl_up(yB, off, 64);
        const float t5 = __shfl_up(zB, off, 64);
        if (lane >= off) { xA += t0; yA += t1; zA += t2; xB += t3; yB += t4; zB += t5; }
    }
    if (half == 0 && lane == 63) {
        wtot[row][0] = xA;     wtot[row][1] = yA;     wtot[row][2] = zA;
        wtot[row + 4][0] = xB; wtot[row + 4][1] = yB; wtot[row + 4][2] = zB;
    }
    __syncthreads();
    if (half == 1) {
        xA += wtot[row][0];     yA += wtot[row][1];     zA += wtot[row][2];
        xB += wtot[row + 4][0]; yB += wtot[row + 4][1]; zB += wtot[row + 4][2];
    }

    // ---- P2a: non-quat stores (pos, zeros, t=0 quat) — drain under the chain ----
    float* oA = out + ((size_t)rA * SEQ + s) * SD;
    float* oB = out + ((size_t)rB * SEQ + s) * SD;
    if (vA) {
        oA[0] = ginit[row][0] + xA - dA0;   // exclusive prefix = inclusive - own
        oA[1] = ginit[row][1] + yA - dA1;
        oA[2] = ginit[row][2] + zA - dA2;
        if (s == 0) {                       // t=0 quat: init_q, NOT normalized
            oA[3] = ginit[row][3]; oA[4] = ginit[row][4];
            oA[5] = ginit[row][5]; oA[6] = ginit[row][6];
        }
#pragma unroll
        for (int k = 7; k < SD; ++k) oA[k] = 0.f;
    }
    if (vB) {
        oB[0] = ginit[row + 4][0] + xB - dB0;
        oB[1] = ginit[row + 4][1] + yB - dB1;
        oB[2] = ginit[row + 4][2] + zB - dB2;
        if (s == 0) {
            oB[3] = ginit[row + 4][3]; oB[4] = ginit[row + 4][4];
            oB[5] = ginit[row + 4][5]; oB[6] = ginit[row + 4][6];
        }
#pragma unroll
        for (int k = 7; k < SD; ++k) oB[k] = 0.f;
    }

    // ---- P2b: all 8 chains, lanes 0..7 of wave 0, one window ----
    if (tid < RPB && base + tid < B) {
        const float4* srow = sdq[tid];
        float4*       qrow = squat[tid];
        float q0 = ginit[tid][3], q1 = ginit[tid][4],
              q2 = ginit[tid][5], q3 = ginit[tid][6];

#define QSTEP(C, T) do {                                                \
            q0 += (C).x; q1 += (C).y; q2 += (C).z; q3 += (C).w;         \
            const float a_ = q0 * q0 + q1 * q1;                         \
            const float b_ = q2 * q2 + q3 * q3;                         \
            const float i_ = __builtin_amdgcn_rsqf(a_ + b_);            \
            q0 *= i_; q1 *= i_; q2 *= i_; q3 *= i_;                     \
            qrow[T] = make_float4(q0, q1, q2, q3);                      \
        } while (0)

        float4 c0 = srow[0], c1 = srow[1], c2 = srow[2], c3 = srow[3],
               c4 = srow[4], c5 = srow[5], c6 = srow[6], c7 = srow[7];
        for (int w = 0; w < 15; ++w) {               // t = 1..120
            const float4* nx = srow + (w + 1) * 8;   // last window: srow[120..127]
            const float4 n0 = nx[0], n1 = nx[1], n2 = nx[2], n3 = nx[3],
                         n4 = nx[4], n5 = nx[5], n6 = nx[6], n7 = nx[7];
            const int t = w * 8 + 1;
            QSTEP(c0, t);     QSTEP(c1, t + 1); QSTEP(c2, t + 2); QSTEP(c3, t + 3);
            QSTEP(c4, t + 4); QSTEP(c5, t + 5); QSTEP(c6, t + 6); QSTEP(c7, t + 7);
            c0 = n0; c1 = n1; c2 = n2; c3 = n3;
            c4 = n4; c5 = n5; c6 = n6; c7 = n7;
        }
        QSTEP(c0, 121); QSTEP(c1, 122); QSTEP(c2, 123); QSTEP(c3, 124);
        QSTEP(c4, 125); QSTEP(c5, 126); QSTEP(c6, 127);
#undef QSTEP
    }
    __syncthreads();

    // ---- P3: quat stores only — merge into L2-dirty lines from P2a ----
    if (vA && s > 0) {
        const float4 q = squat[row][s];
        oA[3] = q.x; oA[4] = q.y; oA[5] = q.z; oA[6] = q.w;
    }
    if (vB && s > 0) {
        const float4 q = squat[row + 4][s];
        oB[3] = q.x; oB[4] = q.y; oB[5] = q.z; oB[6] = q.w;
    }
}

extern "C" void kernel_launch(void* const* d_in, const int* in_sizes, int n_in,
                              void* d_out, int out_size, void* d_ws, size_t ws_size,
                              hipStream_t stream) {
    const float* dba = (const float*)d_in[0];   // (B, 128, 32)
    // d_in[1] = imu_measurements — unused by the reference
    const float* gt  = (const float*)d_in[2];   // (B, 128, 15)
    float* out = (float*)d_out;                 // (B, 128, 15)

    const int B = in_sizes[0] / (SEQ * REC);
    const int blocks = (B + RPB - 1) / RPB;     // 512 @ B=4096 -> 2 blocks/CU
    fused_kernel<<<blocks, NT, 0, stream>>>(dba, gt, out, B);
}